// Round 5
// baseline (4887.758 us; speedup 1.0000x reference)
//
#include <hip/hip_runtime.h>
#include <hip/hip_bf16.h>

#define N_   100000
#define E_   1200000
#define GG   1000
#define CSTRIDE 9344   // A(4096) + B(4096) + C(1024) + c0(64) + d0(64)
#define SCAN_B 1024
#define NB_SCAN ((N_ + SCAN_B - 1) / SCAN_B)   // 98

__device__ __forceinline__ float rl(float v, int k) {
  return __uint_as_float(__builtin_amdgcn_readlane(__float_as_uint(v), k));
}

// ---------- graph boundaries from sorted batch (no atomics) ----------
__global__ void k_gstart(const int* __restrict__ batch, int* __restrict__ gstart) {
  for (int i = blockIdx.x * blockDim.x + threadIdx.x; i < N_; i += gridDim.x * blockDim.x) {
    int b = batch[i];
    if (i == 0) {
      for (int g = 0; g <= b; ++g) gstart[g] = 0;
    } else {
      int bp = batch[i - 1];
      for (int g = bp + 1; g <= b; ++g) gstart[g] = i;
    }
    if (i == N_ - 1) {
      for (int g = b + 1; g <= GG; ++g) gstart[g] = N_;
    }
  }
}

// ---------- CSR build ----------
__global__ void k_deg(const int* __restrict__ dst, int* __restrict__ cnt) {
  for (int e = blockIdx.x * blockDim.x + threadIdx.x; e < E_; e += gridDim.x * blockDim.x)
    atomicAdd(&cnt[dst[e]], 1);
}

__global__ void k_scan1(const int* __restrict__ cnt, int* __restrict__ rowptr,
                        int* __restrict__ bsum) {
  __shared__ int s[SCAN_B];
  int t = threadIdx.x, i = blockIdx.x * SCAN_B + t;
  int v = (i < N_) ? cnt[i] : 0;
  s[t] = v;
  __syncthreads();
  for (int off = 1; off < SCAN_B; off <<= 1) {
    int x = (t >= off) ? s[t - off] : 0;
    __syncthreads();
    s[t] += x;
    __syncthreads();
  }
  if (i < N_) rowptr[i] = s[t] - v;           // block-local exclusive
  if (t == SCAN_B - 1) bsum[blockIdx.x] = s[t];
}

__global__ void k_scan2(int* __restrict__ bsum) {
  __shared__ int s[SCAN_B];
  int t = threadIdx.x;
  int v = (t < NB_SCAN) ? bsum[t] : 0;
  s[t] = v;
  __syncthreads();
  for (int off = 1; off < SCAN_B; off <<= 1) {
    int x = (t >= off) ? s[t - off] : 0;
    __syncthreads();
    s[t] += x;
    __syncthreads();
  }
  if (t < NB_SCAN) bsum[t] = s[t] - v;        // exclusive block offsets
}

__global__ void k_scan3(int* __restrict__ rowptr, const int* __restrict__ bsum) {
  int t = threadIdx.x, i = blockIdx.x * SCAN_B + t;
  if (i < N_) rowptr[i] += bsum[blockIdx.x];
  if (i == 0) rowptr[N_] = E_;
}

__global__ void k_fill(const int* __restrict__ dst, const int* __restrict__ rowptr,
                       int* __restrict__ pos, int* __restrict__ adj) {
  for (int e = blockIdx.x * blockDim.x + threadIdx.x; e < E_; e += gridDim.x * blockDim.x) {
    int d = dst[e];
    int slot = atomicAdd(&pos[d], 1);
    adj[rowptr[d] + slot] = e;   // store EDGE id
  }
}

// ---------- aea[d][k] = sum of edge_attr over incoming edges (gather) ----------
__global__ void k_aeag(const int* __restrict__ rowptr, const int* __restrict__ adj,
                       const float* __restrict__ ea, float* __restrict__ aea) {
  int lane = threadIdx.x & 63, w = threadIdx.x >> 6;
  int q = lane >> 4, j = lane & 15;
  int gw = blockIdx.x * 4 + w, nwv = gridDim.x * 4;
  for (int n = gw; n < N_; n += nwv) {
    int rp = rowptr[n], rp1 = rowptr[n + 1];
    float acc = 0.f;
    for (int idx = rp + q; idx < rp1; idx += 4) {
      int e = adj[idx];
      acc += ea[e * 16 + j];
    }
    acc += __shfl_xor(acc, 16);
    acc += __shfl_xor(acc, 32);
    if (q == 0) aea[n * 16 + j] = acc;
  }
}

// ---------- fold layer constants ----------
__global__ void k_setup(const float* __restrict__ nodeW, const float* __restrict__ nodeB,
                        const float* __restrict__ edgeW, const float* __restrict__ edgeB,
                        const float* __restrict__ m1W, const float* __restrict__ m1B,
                        float* __restrict__ cst) {
  int l = blockIdx.x;
  __shared__ float sWn[4096], sWe[1024], sW1[8192];
  const float* Wn = nodeW + l * 4096;
  const float* We = edgeW + l * 1024;
  const float* W1 = m1W + l * 8192;
  for (int i = threadIdx.x; i < 4096; i += 256) sWn[i] = Wn[i];
  for (int i = threadIdx.x; i < 1024; i += 256) sWe[i] = We[i];
  for (int i = threadIdx.x; i < 8192; i += 256) sW1[i] = W1[i];
  __syncthreads();
  float* C = cst + l * CSTRIDE;
  int j = threadIdx.x & 63, q = threadIdx.x >> 6;
  for (int kk = 0; kk < 16; ++kk) {
    int k = q * 16 + kk;
    float a = 0.f, b = 0.f;
    for (int m = 0; m < 64; ++m) {
      float w = sWn[k * 64 + m];
      a += w * sW1[m * 64 + j];
      b += w * sW1[(64 + m) * 64 + j];
    }
    C[k * 64 + j] = a;
    C[4096 + k * 64 + j] = b;
  }
  if (q == 0) {
    for (int k = 0; k < 16; ++k) {
      float c = 0.f;
      for (int m = 0; m < 64; ++m) c += sWe[k * 64 + m] * sW1[(64 + m) * 64 + j];
      C[8192 + k * 64 + j] = c;
    }
  } else if (q == 1) {
    float c = 0.f;
    for (int m = 0; m < 64; ++m)
      c += (nodeB[l * 64 + m] + edgeB[l * 64 + m]) * sW1[(64 + m) * 64 + j];
    C[9216 + j] = c;
  } else if (q == 2) {
    float d = m1B[l * 64 + j];
    for (int m = 0; m < 64; ++m) d += nodeB[l * 64 + m] * sW1[m * 64 + j];
    C[9280 + j] = d;
  }
}

// ---------- encoder ----------
__global__ void k_enc(const float* __restrict__ x, const float* __restrict__ W,
                      const float* __restrict__ b, float* __restrict__ out) {
  __shared__ float sW[4096];
  __shared__ float sb[64];
  for (int i = threadIdx.x; i < 4096; i += 256) sW[i] = W[i];
  if (threadIdx.x < 64) sb[threadIdx.x] = b[threadIdx.x];
  __syncthreads();
  int j = threadIdx.x & 63, w = threadIdx.x >> 6;
  int gw = blockIdx.x * 4 + w, nwv = gridDim.x * 4;
  for (int p = gw; p < N_ / 2; p += nwv) {
    int nA = p * 2, nB = nA + 1;
    float xA = x[nA * 64 + j];
    float xB = x[nB * 64 + j];
    float aA = sb[j], aB = sb[j];
#pragma unroll
    for (int k = 0; k < 64; ++k) {
      float wv = sW[k * 64 + j];
      aA += rl(xA, k) * wv;
      aB += rl(xB, k) * wv;
    }
    out[nA * 64 + j] = aA;
    out[nB * 64 + j] = aB;
  }
}

// ---------- per-layer: fused gather + node MLP (NO atomics) ----------
__global__ void k_nodeg(const float* __restrict__ h, const int* __restrict__ rowptr,
                        const int* __restrict__ adj, const int* __restrict__ srcI,
                        const float* __restrict__ aea,
                        const float* __restrict__ cst, const float* __restrict__ W2,
                        const float* __restrict__ b2, float* __restrict__ h2) {
  __shared__ float sA[4096], sB[4096], sW2[4096], sC[1024];
  __shared__ float sc0[64], sd0[64], sb2[64];
  for (int i = threadIdx.x; i < 4096; i += 256) {
    sA[i] = cst[i];
    sB[i] = cst[4096 + i];
    sW2[i] = W2[i];
  }
  for (int i = threadIdx.x; i < 1024; i += 256) sC[i] = cst[8192 + i];
  if (threadIdx.x < 64) {
    sc0[threadIdx.x] = cst[9216 + threadIdx.x];
    sd0[threadIdx.x] = cst[9280 + threadIdx.x];
    sb2[threadIdx.x] = b2[threadIdx.x];
  }
  __syncthreads();
  int j = threadIdx.x & 63, w = threadIdx.x >> 6;
  int gw = blockIdx.x * 4 + w, nwv = gridDim.x * 4;
  for (int p = gw; p < N_ / 2; p += nwv) {     // N_ even: nB always valid
    int nA = 2 * p, nB = nA + 1;
    float xA = h[nA * 64 + j];
    float xB = h[nB * 64 + j];
    int rA0 = rowptr[nA], rA1 = rowptr[nA + 1], rB1 = rowptr[nB + 1];
    // gather neighbor sums (replaces the old atomic scatter)
    float yA = 0.f, yB = 0.f;
#pragma unroll 4
    for (int idx = rA0; idx < rA1; ++idx) {
      int e = adj[idx];
      int s = __builtin_amdgcn_readfirstlane(srcI[e]);
      yA += h[s * 64 + j];
    }
#pragma unroll 4
    for (int idx = rA1; idx < rB1; ++idx) {
      int e = adj[idx];
      int s = __builtin_amdgcn_readfirstlane(srcI[e]);
      yB += h[s * 64 + j];
    }
    float eA = (j < 16) ? aea[nA * 16 + j] : 0.f;
    float eB = (j < 16) ? aea[nB * 16 + j] : 0.f;
    float dgA = (float)(rA1 - rA0);
    float dgB = (float)(rB1 - rA1);
    float accA = sd0[j] + dgA * sc0[j];
    float accB = sd0[j] + dgB * sc0[j];
#pragma unroll
    for (int k = 0; k < 64; ++k) {
      float wv = sA[k * 64 + j];
      accA += rl(xA, k) * wv;
      accB += rl(xB, k) * wv;
    }
#pragma unroll
    for (int k = 0; k < 64; ++k) {
      float wv = sB[k * 64 + j];
      accA += rl(yA, k) * wv;
      accB += rl(yB, k) * wv;
    }
#pragma unroll
    for (int k = 0; k < 16; ++k) {
      float wv = sC[k * 64 + j];
      accA += rl(eA, k) * wv;
      accB += rl(eB, k) * wv;
    }
    float tA = fmaxf(accA, 0.f), tB = fmaxf(accB, 0.f);
    float oA = sb2[j], oB = sb2[j];
#pragma unroll
    for (int k = 0; k < 64; ++k) {
      float wv = sW2[k * 64 + j];
      oA += rl(tA, k) * wv;
      oB += rl(tB, k) * wv;
    }
    h2[nA * 64 + j] = oA;
    h2[nB * 64 + j] = oB;
  }
}

// ---------- per-layer: per-graph stats (block per graph, NO atomics) ----------
__global__ void k_gstats(const float* __restrict__ h2, const int* __restrict__ gstart,
                         float* __restrict__ mean, float* __restrict__ rstd) {
  int g = blockIdx.x;
  int s0 = gstart[g], s1 = gstart[g + 1];
  int j = threadIdx.x & 63, w = threadIdx.x >> 6;
  float sm = 0.f, sq = 0.f;
  for (int r = s0 + w; r < s1; r += 4) {
    float v = h2[r * 64 + j];
    sm += v;
    sq += v * v;
  }
  __shared__ float ls[4][64], lq[4][64];
  ls[w][j] = sm;
  lq[w][j] = sq;
  __syncthreads();
  if (w == 0) {
    sm = ls[0][j] + ls[1][j] + ls[2][j] + ls[3][j];
    sq = lq[0][j] + lq[1][j] + lq[2][j] + lq[3][j];
    float c = (float)max(s1 - s0, 1);
    float m = sm / c;
    float var = sq / c - m * m;
    mean[g * 64 + j] = m;
    rstd[g * 64 + j] = rsqrtf(var + 1e-5f);
  }
}

// ---------- per-layer: norm + relu + residual ----------
__global__ void k_fin(const float* __restrict__ h2, const int* __restrict__ batch,
                      const float* __restrict__ mean, const float* __restrict__ rstd,
                      const float* __restrict__ nw_, const float* __restrict__ nb_,
                      float* __restrict__ h) {
  int total = N_ * 64;
  for (int i = blockIdx.x * blockDim.x + threadIdx.x; i < total; i += gridDim.x * blockDim.x) {
    int n = i >> 6, j = i & 63;
    int g = batch[n];
    float val = nw_[j] * (h2[i] - mean[g * 64 + j]) * rstd[g * 64 + j] + nb_[j];
    h[i] = fmaxf(val, 0.f) + h[i];
  }
}

// ---------- launch ----------
extern "C" void kernel_launch(void* const* d_in, const int* in_sizes, int n_in,
                              void* d_out, int out_size, void* d_ws, size_t ws_size,
                              hipStream_t stream) {
  const float* x     = (const float*)d_in[0];
  const int*   eidx  = (const int*)d_in[1];
  const float* eattr = (const float*)d_in[2];
  const int*   batch = (const int*)d_in[3];
  const float* encW  = (const float*)d_in[4];
  const float* encB  = (const float*)d_in[5];
  const float* nodeW = (const float*)d_in[6];
  const float* nodeB = (const float*)d_in[7];
  const float* edgeW = (const float*)d_in[8];
  const float* edgeB = (const float*)d_in[9];
  const float* m1W   = (const float*)d_in[10];
  const float* m1B   = (const float*)d_in[11];
  const float* m2W   = (const float*)d_in[12];
  const float* m2B   = (const float*)d_in[13];
  const float* nw    = (const float*)d_in[14];
  const float* nb    = (const float*)d_in[15];

  float* h  = (float*)d_out;
  float* ws = (float*)d_ws;
  float* h2   = ws;                       // N*64
  float* aea  = h2 + N_ * 64;             // N*16
  float* mean = aea + N_ * 16;            // G*64
  float* rstd = mean + GG * 64;           // G*64
  float* cst  = rstd + GG * 64;           // 3*CSTRIDE
  int* rowptr = (int*)(cst + 3 * CSTRIDE);   // N+1
  int* cntP   = rowptr + (N_ + 1);           // N (deg counts, then reused as pos)
  int* bsum   = cntP + N_;                   // 128
  int* gstart = bsum + 128;                  // G+1
  int* adj    = gstart + (GG + 1);           // E

  const int* srcI = eidx;
  const int* dstI = eidx + E_;

  // boundaries + CSR build (once per call; d_ws is re-poisoned each call)
  k_gstart<<<512, 256, 0, stream>>>(batch, gstart);
  hipMemsetAsync(cntP, 0, (size_t)N_ * 4, stream);
  k_deg<<<1024, 256, 0, stream>>>(dstI, cntP);
  k_scan1<<<NB_SCAN, SCAN_B, 0, stream>>>(cntP, rowptr, bsum);
  k_scan2<<<1, SCAN_B, 0, stream>>>(bsum);
  k_scan3<<<NB_SCAN, SCAN_B, 0, stream>>>(rowptr, bsum);
  hipMemsetAsync(cntP, 0, (size_t)N_ * 4, stream);
  k_fill<<<1024, 256, 0, stream>>>(dstI, rowptr, cntP, adj);
  k_aeag<<<1024, 256, 0, stream>>>(rowptr, adj, eattr, aea);

  k_setup<<<3, 256, 0, stream>>>(nodeW, nodeB, edgeW, edgeB, m1W, m1B, cst);
  k_enc<<<1024, 256, 0, stream>>>(x, encW, encB, h);

  for (int l = 0; l < 3; ++l) {
    k_nodeg<<<1024, 256, 0, stream>>>(h, rowptr, adj, srcI, aea, cst + l * CSTRIDE,
                                      m2W + l * 4096, m2B + l * 64, h2);
    k_gstats<<<GG, 256, 0, stream>>>(h2, gstart, mean, rstd);
    k_fin<<<2048, 256, 0, stream>>>(h2, batch, mean, rstd,
                                    nw + l * 64, nb + l * 64, h);
  }
}

// Round 6
// 3592.203 us; speedup vs baseline: 1.3607x; 1.3607x over previous
//
#include <hip/hip_runtime.h>
#include <hip/hip_bf16.h>

#define N_   100000
#define E_   1200000
#define GG   1000
#define CSTRIDE 9344   // A(4096) + B(4096) + C(1024) + c0(64) + d0(64)
#define SCAN_B 1024
#define NB_SCAN ((N_ + SCAN_B - 1) / SCAN_B)   // 98

__device__ __forceinline__ float rl(float v, int k) {
  return __uint_as_float(__builtin_amdgcn_readlane(__float_as_uint(v), k));
}

// ---------- graph boundaries from sorted batch ----------
__global__ void k_gstart(const int* __restrict__ batch, int* __restrict__ gstart) {
  for (int i = blockIdx.x * blockDim.x + threadIdx.x; i < N_; i += gridDim.x * blockDim.x) {
    int b = batch[i];
    if (i == 0) {
      for (int g = 0; g <= b; ++g) gstart[g] = 0;
    } else {
      int bp = batch[i - 1];
      for (int g = bp + 1; g <= b; ++g) gstart[g] = i;
    }
    if (i == N_ - 1) {
      for (int g = b + 1; g <= GG; ++g) gstart[g] = N_;
    }
  }
}

// ---------- CSR build ----------
__global__ void k_deg(const int* __restrict__ dst, int* __restrict__ cnt) {
  for (int e = blockIdx.x * blockDim.x + threadIdx.x; e < E_; e += gridDim.x * blockDim.x)
    atomicAdd(&cnt[dst[e]], 1);
}

__global__ void k_scan1(const int* __restrict__ cnt, int* __restrict__ rowptr,
                        int* __restrict__ bsum) {
  __shared__ int s[SCAN_B];
  int t = threadIdx.x, i = blockIdx.x * SCAN_B + t;
  int v = (i < N_) ? cnt[i] : 0;
  s[t] = v;
  __syncthreads();
  for (int off = 1; off < SCAN_B; off <<= 1) {
    int x = (t >= off) ? s[t - off] : 0;
    __syncthreads();
    s[t] += x;
    __syncthreads();
  }
  if (i < N_) rowptr[i] = s[t] - v;           // block-local exclusive
  if (t == SCAN_B - 1) bsum[blockIdx.x] = s[t];
}

__global__ void k_scan2(int* __restrict__ bsum) {
  __shared__ int s[SCAN_B];
  int t = threadIdx.x;
  int v = (t < NB_SCAN) ? bsum[t] : 0;
  s[t] = v;
  __syncthreads();
  for (int off = 1; off < SCAN_B; off <<= 1) {
    int x = (t >= off) ? s[t - off] : 0;
    __syncthreads();
    s[t] += x;
    __syncthreads();
  }
  if (t < NB_SCAN) bsum[t] = s[t] - v;        // exclusive block offsets
}

__global__ void k_scan3(int* __restrict__ rowptr, const int* __restrict__ bsum) {
  int t = threadIdx.x, i = blockIdx.x * SCAN_B + t;
  if (i < N_) rowptr[i] += bsum[blockIdx.x];
  if (i == 0) rowptr[N_] = E_;
}

// store src node id AND edge id in CSR slot order
__global__ void k_fill(const int* __restrict__ dst, const int* __restrict__ srcI,
                       const int* __restrict__ rowptr, int* __restrict__ pos,
                       int* __restrict__ adjS, int* __restrict__ adjE) {
  for (int e = blockIdx.x * blockDim.x + threadIdx.x; e < E_; e += gridDim.x * blockDim.x) {
    int d = dst[e];
    int slot = atomicAdd(&pos[d], 1);
    int p = rowptr[d] + slot;
    adjS[p] = srcI[e];
    adjE[p] = e;
  }
}

// ---------- aea[d][k] = sum of edge_attr over incoming edges ----------
__global__ void k_aeag(const int* __restrict__ rowptr, const int* __restrict__ adjE,
                       const float* __restrict__ ea, float* __restrict__ aea) {
  int lane = threadIdx.x & 63, w = threadIdx.x >> 6;
  int q = lane >> 4, j = lane & 15;
  int gw = blockIdx.x * 4 + w, nwv = gridDim.x * 4;
  for (int n = gw; n < N_; n += nwv) {
    int rp = rowptr[n], rp1 = rowptr[n + 1];
    float acc = 0.f;
    for (int idx = rp + q; idx < rp1; idx += 4) {
      int e = adjE[idx];
      acc += ea[e * 16 + j];
    }
    acc += __shfl_xor(acc, 16);
    acc += __shfl_xor(acc, 32);
    if (q == 0) aea[n * 16 + j] = acc;
  }
}

// ---------- fold layer constants ----------
__global__ void k_setup(const float* __restrict__ nodeW, const float* __restrict__ nodeB,
                        const float* __restrict__ edgeW, const float* __restrict__ edgeB,
                        const float* __restrict__ m1W, const float* __restrict__ m1B,
                        float* __restrict__ cst) {
  int l = blockIdx.x;
  __shared__ float sWn[4096], sWe[1024], sW1[8192];
  const float* Wn = nodeW + l * 4096;
  const float* We = edgeW + l * 1024;
  const float* W1 = m1W + l * 8192;
  for (int i = threadIdx.x; i < 4096; i += 256) sWn[i] = Wn[i];
  for (int i = threadIdx.x; i < 1024; i += 256) sWe[i] = We[i];
  for (int i = threadIdx.x; i < 8192; i += 256) sW1[i] = W1[i];
  __syncthreads();
  float* C = cst + l * CSTRIDE;
  int j = threadIdx.x & 63, q = threadIdx.x >> 6;
  for (int kk = 0; kk < 16; ++kk) {
    int k = q * 16 + kk;
    float a = 0.f, b = 0.f;
    for (int m = 0; m < 64; ++m) {
      float w = sWn[k * 64 + m];
      a += w * sW1[m * 64 + j];
      b += w * sW1[(64 + m) * 64 + j];
    }
    C[k * 64 + j] = a;
    C[4096 + k * 64 + j] = b;
  }
  if (q == 0) {
    for (int k = 0; k < 16; ++k) {
      float c = 0.f;
      for (int m = 0; m < 64; ++m) c += sWe[k * 64 + m] * sW1[(64 + m) * 64 + j];
      C[8192 + k * 64 + j] = c;
    }
  } else if (q == 1) {
    float c = 0.f;
    for (int m = 0; m < 64; ++m)
      c += (nodeB[l * 64 + m] + edgeB[l * 64 + m]) * sW1[(64 + m) * 64 + j];
    C[9216 + j] = c;
  } else if (q == 2) {
    float d = m1B[l * 64 + j];
    for (int m = 0; m < 64; ++m) d += nodeB[l * 64 + m] * sW1[m * 64 + j];
    C[9280 + j] = d;
  }
}

// ---------- encoder ----------
__global__ void k_enc(const float* __restrict__ x, const float* __restrict__ W,
                      const float* __restrict__ b, float* __restrict__ out) {
  __shared__ float sW[4096];
  __shared__ float sb[64];
  for (int i = threadIdx.x; i < 4096; i += 256) sW[i] = W[i];
  if (threadIdx.x < 64) sb[threadIdx.x] = b[threadIdx.x];
  __syncthreads();
  int j = threadIdx.x & 63, w = threadIdx.x >> 6;
  int gw = blockIdx.x * 4 + w, nwv = gridDim.x * 4;
  for (int p = gw; p < N_ / 2; p += nwv) {
    int nA = p * 2, nB = nA + 1;
    float xA = x[nA * 64 + j];
    float xB = x[nB * 64 + j];
    float aA = sb[j], aB = sb[j];
#pragma unroll
    for (int k = 0; k < 64; ++k) {
      float wv = sW[k * 64 + j];
      aA += rl(xA, k) * wv;
      aB += rl(xB, k) * wv;
    }
    out[nA * 64 + j] = aA;
    out[nB * 64 + j] = aB;
  }
}

// ---------- per-layer: LEAN neighbor gather: ah[n] = sum_{s in nbrs(n)} h[s] ----------
// Wave per node. One coalesced load of <=64 src ids, then readlane-broadcast
// row loads that are mutually independent (4 accumulator streams).
__global__ __launch_bounds__(256) void k_gather(const float* __restrict__ h,
                                                const int* __restrict__ rowptr,
                                                const int* __restrict__ adjS,
                                                float* __restrict__ ah) {
  int lane = threadIdx.x & 63;
  int gw = blockIdx.x * 4 + (threadIdx.x >> 6), nwv = gridDim.x * 4;
  for (int n = gw; n < N_; n += nwv) {
    int r0 = rowptr[n], r1 = rowptr[n + 1];
    float a0 = 0.f, a1 = 0.f, a2 = 0.f, a3 = 0.f;
    for (int base = r0; base < r1; base += 64) {
      int cnt = r1 - base;
      if (cnt > 64) cnt = 64;
      int idx = base + lane;
      int sv = (idx < r1) ? adjS[idx] : 0;       // coalesced src-id load
      int k = 0;
      for (; k + 3 < cnt; k += 4) {
        int s0 = __builtin_amdgcn_readlane(sv, k);
        int s1 = __builtin_amdgcn_readlane(sv, k + 1);
        int s2 = __builtin_amdgcn_readlane(sv, k + 2);
        int s3 = __builtin_amdgcn_readlane(sv, k + 3);
        a0 += h[s0 * 64 + lane];
        a1 += h[s1 * 64 + lane];
        a2 += h[s2 * 64 + lane];
        a3 += h[s3 * 64 + lane];
      }
      for (; k < cnt; ++k) {
        int sk = __builtin_amdgcn_readlane(sv, k);
        a0 += h[sk * 64 + lane];
      }
    }
    ah[n * 64 + lane] = (a0 + a1) + (a2 + a3);
  }
}

// ---------- per-layer: pure streaming node MLP ----------
__global__ void k_node(const float* __restrict__ h, const float* __restrict__ ah,
                       const float* __restrict__ aea, const int* __restrict__ rowptr,
                       const float* __restrict__ cst, const float* __restrict__ W2,
                       const float* __restrict__ b2, float* __restrict__ h2) {
  __shared__ float sA[4096], sB[4096], sW2[4096], sC[1024];
  __shared__ float sc0[64], sd0[64], sb2[64];
  for (int i = threadIdx.x; i < 4096; i += 256) {
    sA[i] = cst[i];
    sB[i] = cst[4096 + i];
    sW2[i] = W2[i];
  }
  for (int i = threadIdx.x; i < 1024; i += 256) sC[i] = cst[8192 + i];
  if (threadIdx.x < 64) {
    sc0[threadIdx.x] = cst[9216 + threadIdx.x];
    sd0[threadIdx.x] = cst[9280 + threadIdx.x];
    sb2[threadIdx.x] = b2[threadIdx.x];
  }
  __syncthreads();
  int j = threadIdx.x & 63, w = threadIdx.x >> 6;
  int gw = blockIdx.x * 4 + w, nwv = gridDim.x * 4;
  for (int p = gw; p < N_ / 2; p += nwv) {     // N_ even
    int nA = 2 * p, nB = nA + 1;
    float xA = h[nA * 64 + j];
    float xB = h[nB * 64 + j];
    float yA = ah[nA * 64 + j];
    float yB = ah[nB * 64 + j];
    int rA0 = rowptr[nA], rA1 = rowptr[nA + 1], rB1 = rowptr[nB + 1];
    float eA = (j < 16) ? aea[nA * 16 + j] : 0.f;
    float eB = (j < 16) ? aea[nB * 16 + j] : 0.f;
    float dgA = (float)(rA1 - rA0);
    float dgB = (float)(rB1 - rA1);
    float accA = sd0[j] + dgA * sc0[j];
    float accB = sd0[j] + dgB * sc0[j];
#pragma unroll
    for (int k = 0; k < 64; ++k) {
      float wv = sA[k * 64 + j];
      accA += rl(xA, k) * wv;
      accB += rl(xB, k) * wv;
    }
#pragma unroll
    for (int k = 0; k < 64; ++k) {
      float wv = sB[k * 64 + j];
      accA += rl(yA, k) * wv;
      accB += rl(yB, k) * wv;
    }
#pragma unroll
    for (int k = 0; k < 16; ++k) {
      float wv = sC[k * 64 + j];
      accA += rl(eA, k) * wv;
      accB += rl(eB, k) * wv;
    }
    float tA = fmaxf(accA, 0.f), tB = fmaxf(accB, 0.f);
    float oA = sb2[j], oB = sb2[j];
#pragma unroll
    for (int k = 0; k < 64; ++k) {
      float wv = sW2[k * 64 + j];
      oA += rl(tA, k) * wv;
      oB += rl(tB, k) * wv;
    }
    h2[nA * 64 + j] = oA;
    h2[nB * 64 + j] = oB;
  }
}

// ---------- per-layer: per-graph stats (block per graph) ----------
__global__ void k_gstats(const float* __restrict__ h2, const int* __restrict__ gstart,
                         float* __restrict__ mean, float* __restrict__ rstd) {
  int g = blockIdx.x;
  int s0 = gstart[g], s1 = gstart[g + 1];
  int j = threadIdx.x & 63, w = threadIdx.x >> 6;
  float sm = 0.f, sq = 0.f;
  for (int r = s0 + w; r < s1; r += 4) {
    float v = h2[r * 64 + j];
    sm += v;
    sq += v * v;
  }
  __shared__ float ls[4][64], lq[4][64];
  ls[w][j] = sm;
  lq[w][j] = sq;
  __syncthreads();
  if (w == 0) {
    sm = ls[0][j] + ls[1][j] + ls[2][j] + ls[3][j];
    sq = lq[0][j] + lq[1][j] + lq[2][j] + lq[3][j];
    float c = (float)max(s1 - s0, 1);
    float m = sm / c;
    float var = sq / c - m * m;
    mean[g * 64 + j] = m;
    rstd[g * 64 + j] = rsqrtf(var + 1e-5f);
  }
}

// ---------- per-layer: norm + relu + residual ----------
__global__ void k_fin(const float* __restrict__ h2, const int* __restrict__ batch,
                      const float* __restrict__ mean, const float* __restrict__ rstd,
                      const float* __restrict__ nw_, const float* __restrict__ nb_,
                      float* __restrict__ h) {
  int total = N_ * 64;
  for (int i = blockIdx.x * blockDim.x + threadIdx.x; i < total; i += gridDim.x * blockDim.x) {
    int n = i >> 6, j = i & 63;
    int g = batch[n];
    float val = nw_[j] * (h2[i] - mean[g * 64 + j]) * rstd[g * 64 + j] + nb_[j];
    h[i] = fmaxf(val, 0.f) + h[i];
  }
}

// ---------- launch ----------
extern "C" void kernel_launch(void* const* d_in, const int* in_sizes, int n_in,
                              void* d_out, int out_size, void* d_ws, size_t ws_size,
                              hipStream_t stream) {
  const float* x     = (const float*)d_in[0];
  const int*   eidx  = (const int*)d_in[1];
  const float* eattr = (const float*)d_in[2];
  const int*   batch = (const int*)d_in[3];
  const float* encW  = (const float*)d_in[4];
  const float* encB  = (const float*)d_in[5];
  const float* nodeW = (const float*)d_in[6];
  const float* nodeB = (const float*)d_in[7];
  const float* edgeW = (const float*)d_in[8];
  const float* edgeB = (const float*)d_in[9];
  const float* m1W   = (const float*)d_in[10];
  const float* m1B   = (const float*)d_in[11];
  const float* m2W   = (const float*)d_in[12];
  const float* m2B   = (const float*)d_in[13];
  const float* nw    = (const float*)d_in[14];
  const float* nb    = (const float*)d_in[15];

  float* h  = (float*)d_out;
  float* ws = (float*)d_ws;
  float* h2   = ws;                       // N*64
  float* ah   = h2 + N_ * 64;             // N*64
  float* aea  = ah + N_ * 64;             // N*16
  float* mean = aea + N_ * 16;            // G*64
  float* rstd = mean + GG * 64;           // G*64
  float* cst  = rstd + GG * 64;           // 3*CSTRIDE
  int* rowptr = (int*)(cst + 3 * CSTRIDE);   // N+1
  int* cntP   = rowptr + (N_ + 1);           // N
  int* bsum   = cntP + N_;                   // 128
  int* gstart = bsum + 128;                  // G+1
  int* adjS   = gstart + (GG + 1);           // E (src ids in CSR order)
  int* adjE   = adjS + E_;                   // E (edge ids in CSR order)

  const int* srcI = eidx;
  const int* dstI = eidx + E_;

  // boundaries + CSR build (once per call)
  k_gstart<<<512, 256, 0, stream>>>(batch, gstart);
  hipMemsetAsync(cntP, 0, (size_t)N_ * 4, stream);
  k_deg<<<1024, 256, 0, stream>>>(dstI, cntP);
  k_scan1<<<NB_SCAN, SCAN_B, 0, stream>>>(cntP, rowptr, bsum);
  k_scan2<<<1, SCAN_B, 0, stream>>>(bsum);
  k_scan3<<<NB_SCAN, SCAN_B, 0, stream>>>(rowptr, bsum);
  hipMemsetAsync(cntP, 0, (size_t)N_ * 4, stream);
  k_fill<<<1024, 256, 0, stream>>>(dstI, srcI, rowptr, cntP, adjS, adjE);
  k_aeag<<<1024, 256, 0, stream>>>(rowptr, adjE, eattr, aea);

  k_setup<<<3, 256, 0, stream>>>(nodeW, nodeB, edgeW, edgeB, m1W, m1B, cst);
  k_enc<<<1024, 256, 0, stream>>>(x, encW, encB, h);

  for (int l = 0; l < 3; ++l) {
    k_gather<<<2048, 256, 0, stream>>>(h, rowptr, adjS, ah);
    k_node<<<1024, 256, 0, stream>>>(h, ah, aea, rowptr, cst + l * CSTRIDE,
                                     m2W + l * 4096, m2B + l * 64, h2);
    k_gstats<<<GG, 256, 0, stream>>>(h2, gstart, mean, rstd);
    k_fin<<<2048, 256, 0, stream>>>(h2, batch, mean, rstd,
                                    nw + l * 64, nb + l * 64, h);
  }
}

// Round 7
// 963.798 us; speedup vs baseline: 5.0714x; 3.7271x over previous
//
#include <hip/hip_runtime.h>
#include <hip/hip_bf16.h>

#define N_   100000
#define E_   1200000
#define GG   1000
#define CSTRIDE 9344   // A(4096) + B(4096) + C(1024) + c0(64) + d0(64)
#define SCAN_B 1024
#define NB_SCAN ((N_ + SCAN_B - 1) / SCAN_B)   // 98

// ---------- graph boundaries from sorted batch ----------
__global__ void k_gstart(const int* __restrict__ batch, int* __restrict__ gstart) {
  for (int i = blockIdx.x * blockDim.x + threadIdx.x; i < N_; i += gridDim.x * blockDim.x) {
    int b = batch[i];
    if (i == 0) {
      for (int g = 0; g <= b; ++g) gstart[g] = 0;
    } else {
      int bp = batch[i - 1];
      for (int g = bp + 1; g <= b; ++g) gstart[g] = i;
    }
    if (i == N_ - 1) {
      for (int g = b + 1; g <= GG; ++g) gstart[g] = N_;
    }
  }
}

// ---------- CSR build ----------
__global__ void k_deg(const int* __restrict__ dst, int* __restrict__ cnt) {
  for (int e = blockIdx.x * blockDim.x + threadIdx.x; e < E_; e += gridDim.x * blockDim.x)
    atomicAdd(&cnt[dst[e]], 1);
}

__global__ void k_scan1(const int* __restrict__ cnt, int* __restrict__ rowptr,
                        int* __restrict__ bsum) {
  __shared__ int s[SCAN_B];
  int t = threadIdx.x, i = blockIdx.x * SCAN_B + t;
  int v = (i < N_) ? cnt[i] : 0;
  s[t] = v;
  __syncthreads();
  for (int off = 1; off < SCAN_B; off <<= 1) {
    int x = (t >= off) ? s[t - off] : 0;
    __syncthreads();
    s[t] += x;
    __syncthreads();
  }
  if (i < N_) rowptr[i] = s[t] - v;           // block-local exclusive
  if (t == SCAN_B - 1) bsum[blockIdx.x] = s[t];
}

__global__ void k_scan2(int* __restrict__ bsum) {
  __shared__ int s[SCAN_B];
  int t = threadIdx.x;
  int v = (t < NB_SCAN) ? bsum[t] : 0;
  s[t] = v;
  __syncthreads();
  for (int off = 1; off < SCAN_B; off <<= 1) {
    int x = (t >= off) ? s[t - off] : 0;
    __syncthreads();
    s[t] += x;
    __syncthreads();
  }
  if (t < NB_SCAN) bsum[t] = s[t] - v;        // exclusive block offsets
}

__global__ void k_scan3(int* __restrict__ rowptr, const int* __restrict__ bsum) {
  int t = threadIdx.x, i = blockIdx.x * SCAN_B + t;
  if (i < N_) rowptr[i] += bsum[blockIdx.x];
  if (i == 0) rowptr[N_] = E_;
}

// store src node id AND edge id in CSR slot order
__global__ void k_fill(const int* __restrict__ dst, const int* __restrict__ srcI,
                       const int* __restrict__ rowptr, int* __restrict__ pos,
                       int* __restrict__ adjS, int* __restrict__ adjE) {
  for (int e = blockIdx.x * blockDim.x + threadIdx.x; e < E_; e += gridDim.x * blockDim.x) {
    int d = dst[e];
    int slot = atomicAdd(&pos[d], 1);
    int p = rowptr[d] + slot;
    adjS[p] = srcI[e];
    adjE[p] = e;
  }
}

// ---------- aea[d][k] = sum of edge_attr over incoming edges ----------
__global__ void k_aeag(const int* __restrict__ rowptr, const int* __restrict__ adjE,
                       const float* __restrict__ ea, float* __restrict__ aea) {
  int lane = threadIdx.x & 63, w = threadIdx.x >> 6;
  int q = lane >> 4, j = lane & 15;
  int gw = blockIdx.x * 4 + w, nwv = gridDim.x * 4;
  for (int n = gw; n < N_; n += nwv) {
    int rp = rowptr[n], rp1 = rowptr[n + 1];
    float acc = 0.f;
    for (int idx = rp + q; idx < rp1; idx += 4) {
      int e = adjE[idx];
      acc += ea[e * 16 + j];
    }
    acc += __shfl_xor(acc, 16);
    acc += __shfl_xor(acc, 32);
    if (q == 0) aea[n * 16 + j] = acc;
  }
}

// ---------- fold layer constants ----------
__global__ void k_setup(const float* __restrict__ nodeW, const float* __restrict__ nodeB,
                        const float* __restrict__ edgeW, const float* __restrict__ edgeB,
                        const float* __restrict__ m1W, const float* __restrict__ m1B,
                        float* __restrict__ cst) {
  int l = blockIdx.x;
  __shared__ float sWn[4096], sWe[1024], sW1[8192];
  const float* Wn = nodeW + l * 4096;
  const float* We = edgeW + l * 1024;
  const float* W1 = m1W + l * 8192;
  for (int i = threadIdx.x; i < 4096; i += 256) sWn[i] = Wn[i];
  for (int i = threadIdx.x; i < 1024; i += 256) sWe[i] = We[i];
  for (int i = threadIdx.x; i < 8192; i += 256) sW1[i] = W1[i];
  __syncthreads();
  float* C = cst + l * CSTRIDE;
  int j = threadIdx.x & 63, q = threadIdx.x >> 6;
  for (int kk = 0; kk < 16; ++kk) {
    int k = q * 16 + kk;
    float a = 0.f, b = 0.f;
    for (int m = 0; m < 64; ++m) {
      float w = sWn[k * 64 + m];
      a += w * sW1[m * 64 + j];
      b += w * sW1[(64 + m) * 64 + j];
    }
    C[k * 64 + j] = a;
    C[4096 + k * 64 + j] = b;
  }
  if (q == 0) {
    for (int k = 0; k < 16; ++k) {
      float c = 0.f;
      for (int m = 0; m < 64; ++m) c += sWe[k * 64 + m] * sW1[(64 + m) * 64 + j];
      C[8192 + k * 64 + j] = c;
    }
  } else if (q == 1) {
    float c = 0.f;
    for (int m = 0; m < 64; ++m)
      c += (nodeB[l * 64 + m] + edgeB[l * 64 + m]) * sW1[(64 + m) * 64 + j];
    C[9216 + j] = c;
  } else if (q == 2) {
    float d = m1B[l * 64 + j];
    for (int m = 0; m < 64; ++m) d += nodeB[l * 64 + m] * sW1[m * 64 + j];
    C[9280 + j] = d;
  }
}

// ---------- encoder: LDS x-stage + uniform broadcast (no readlane) ----------
__global__ __launch_bounds__(256, 2) void k_enc(const float* __restrict__ x,
                                                const float* __restrict__ W,
                                                const float* __restrict__ b,
                                                float* __restrict__ out) {
  __shared__ float sW[4096];
  __shared__ float sb[64];
  __shared__ float xsh[4][64];
  for (int i = threadIdx.x; i < 4096; i += 256) sW[i] = W[i];
  if (threadIdx.x < 64) sb[threadIdx.x] = b[threadIdx.x];
  __syncthreads();
  int j = threadIdx.x & 63, w = threadIdx.x >> 6;
  int gw = blockIdx.x * 4 + w, nwv = gridDim.x * 4;
  for (int n = gw; n < N_; n += nwv) {
    xsh[w][j] = x[n * 64 + j];
    float acc = sb[j];
#pragma unroll
    for (int k = 0; k < 64; k += 4) {
      float4 xk = *(const float4*)&xsh[w][k];
      acc += xk.x * sW[(k + 0) * 64 + j];
      acc += xk.y * sW[(k + 1) * 64 + j];
      acc += xk.z * sW[(k + 2) * 64 + j];
      acc += xk.w * sW[(k + 3) * 64 + j];
    }
    out[n * 64 + j] = acc;
  }
}

// ---------- per-layer: LEAN neighbor gather ----------
__global__ __launch_bounds__(256) void k_gather(const float* __restrict__ h,
                                                const int* __restrict__ rowptr,
                                                const int* __restrict__ adjS,
                                                float* __restrict__ ah) {
  int lane = threadIdx.x & 63;
  int gw = blockIdx.x * 4 + (threadIdx.x >> 6), nwv = gridDim.x * 4;
  for (int n = gw; n < N_; n += nwv) {
    int r0 = rowptr[n], r1 = rowptr[n + 1];
    float a0 = 0.f, a1 = 0.f, a2 = 0.f, a3 = 0.f;
    for (int base = r0; base < r1; base += 64) {
      int cnt = r1 - base;
      if (cnt > 64) cnt = 64;
      int idx = base + lane;
      int sv = (idx < r1) ? adjS[idx] : 0;
      int k = 0;
      for (; k + 3 < cnt; k += 4) {
        int s0 = __builtin_amdgcn_readlane(sv, k);
        int s1 = __builtin_amdgcn_readlane(sv, k + 1);
        int s2 = __builtin_amdgcn_readlane(sv, k + 2);
        int s3 = __builtin_amdgcn_readlane(sv, k + 3);
        a0 += h[s0 * 64 + lane];
        a1 += h[s1 * 64 + lane];
        a2 += h[s2 * 64 + lane];
        a3 += h[s3 * 64 + lane];
      }
      for (; k < cnt; ++k) {
        int sk = __builtin_amdgcn_readlane(sv, k);
        a0 += h[sk * 64 + lane];
      }
    }
    ah[n * 64 + lane] = (a0 + a1) + (a2 + a3);
  }
}

// ---------- per-layer: node MLP via LDS broadcast (no readlane, low live-set) ----------
__global__ __launch_bounds__(256, 2) void k_node(const float* __restrict__ h,
                                                 const float* __restrict__ ah,
                                                 const float* __restrict__ aea,
                                                 const int* __restrict__ rowptr,
                                                 const float* __restrict__ cst,
                                                 const float* __restrict__ W2,
                                                 const float* __restrict__ b2,
                                                 float* __restrict__ h2) {
  __shared__ float sA[4096], sB[4096], sW2[4096], sC[1024];
  __shared__ float sc0[64], sd0[64], sb2[64];
  __shared__ float xs[4][2][160];   // per wave, per node: [0:64)=x, [64:128)=y, [128:144)=e
  for (int i = threadIdx.x; i < 4096; i += 256) {
    sA[i] = cst[i];
    sB[i] = cst[4096 + i];
    sW2[i] = W2[i];
  }
  for (int i = threadIdx.x; i < 1024; i += 256) sC[i] = cst[8192 + i];
  if (threadIdx.x < 64) {
    sc0[threadIdx.x] = cst[9216 + threadIdx.x];
    sd0[threadIdx.x] = cst[9280 + threadIdx.x];
    sb2[threadIdx.x] = b2[threadIdx.x];
  }
  __syncthreads();
  int j = threadIdx.x & 63, w = threadIdx.x >> 6;
  // contiguous pair-chunk per block (round-3's layout was faster; L2 locality)
  int chunk = (((N_ / 2 + gridDim.x - 1) / gridDim.x) + 3) & ~3;
  int p0 = blockIdx.x * chunk;
  int p1 = p0 + chunk; if (p1 > N_ / 2) p1 = N_ / 2;
  for (int p = p0 + w; p < p1; p += 4) {
    int nA = 2 * p, nB = nA + 1;
    xs[w][0][j] = h[nA * 64 + j];
    xs[w][1][j] = h[nB * 64 + j];
    xs[w][0][64 + j] = ah[nA * 64 + j];
    xs[w][1][64 + j] = ah[nB * 64 + j];
    if (j < 16) {
      xs[w][0][128 + j] = aea[nA * 16 + j];
      xs[w][1][128 + j] = aea[nB * 16 + j];
    }
    int rA0 = rowptr[nA], rA1 = rowptr[nA + 1], rB1 = rowptr[nB + 1];
    float accA = sd0[j] + (float)(rA1 - rA0) * sc0[j];
    float accB = sd0[j] + (float)(rB1 - rA1) * sc0[j];
#pragma unroll
    for (int k = 0; k < 64; k += 4) {
      float4 xa = *(const float4*)&xs[w][0][k];
      float4 xb = *(const float4*)&xs[w][1][k];
      float w0 = sA[(k + 0) * 64 + j], w1 = sA[(k + 1) * 64 + j];
      float w2 = sA[(k + 2) * 64 + j], w3 = sA[(k + 3) * 64 + j];
      accA += xa.x * w0 + xa.y * w1 + xa.z * w2 + xa.w * w3;
      accB += xb.x * w0 + xb.y * w1 + xb.z * w2 + xb.w * w3;
    }
#pragma unroll
    for (int k = 0; k < 64; k += 4) {
      float4 xa = *(const float4*)&xs[w][0][64 + k];
      float4 xb = *(const float4*)&xs[w][1][64 + k];
      float w0 = sB[(k + 0) * 64 + j], w1 = sB[(k + 1) * 64 + j];
      float w2 = sB[(k + 2) * 64 + j], w3 = sB[(k + 3) * 64 + j];
      accA += xa.x * w0 + xa.y * w1 + xa.z * w2 + xa.w * w3;
      accB += xb.x * w0 + xb.y * w1 + xb.z * w2 + xb.w * w3;
    }
#pragma unroll
    for (int k = 0; k < 16; k += 4) {
      float4 xa = *(const float4*)&xs[w][0][128 + k];
      float4 xb = *(const float4*)&xs[w][1][128 + k];
      float w0 = sC[(k + 0) * 64 + j], w1 = sC[(k + 1) * 64 + j];
      float w2 = sC[(k + 2) * 64 + j], w3 = sC[(k + 3) * 64 + j];
      accA += xa.x * w0 + xa.y * w1 + xa.z * w2 + xa.w * w3;
      accB += xb.x * w0 + xb.y * w1 + xb.z * w2 + xb.w * w3;
    }
    // relu, re-stage t into xs, GEMM2
    xs[w][0][j] = fmaxf(accA, 0.f);
    xs[w][1][j] = fmaxf(accB, 0.f);
    float oA = sb2[j], oB = sb2[j];
#pragma unroll
    for (int k = 0; k < 64; k += 4) {
      float4 ta = *(const float4*)&xs[w][0][k];
      float4 tb = *(const float4*)&xs[w][1][k];
      float w0 = sW2[(k + 0) * 64 + j], w1 = sW2[(k + 1) * 64 + j];
      float w2 = sW2[(k + 2) * 64 + j], w3 = sW2[(k + 3) * 64 + j];
      oA += ta.x * w0 + ta.y * w1 + ta.z * w2 + ta.w * w3;
      oB += tb.x * w0 + tb.y * w1 + tb.z * w2 + tb.w * w3;
    }
    h2[nA * 64 + j] = oA;
    h2[nB * 64 + j] = oB;
  }
}

// ---------- per-layer: per-graph stats (block per graph) ----------
__global__ void k_gstats(const float* __restrict__ h2, const int* __restrict__ gstart,
                         float* __restrict__ mean, float* __restrict__ rstd) {
  int g = blockIdx.x;
  int s0 = gstart[g], s1 = gstart[g + 1];
  int j = threadIdx.x & 63, w = threadIdx.x >> 6;
  float sm = 0.f, sq = 0.f;
  for (int r = s0 + w; r < s1; r += 4) {
    float v = h2[r * 64 + j];
    sm += v;
    sq += v * v;
  }
  __shared__ float ls[4][64], lq[4][64];
  ls[w][j] = sm;
  lq[w][j] = sq;
  __syncthreads();
  if (w == 0) {
    sm = ls[0][j] + ls[1][j] + ls[2][j] + ls[3][j];
    sq = lq[0][j] + lq[1][j] + lq[2][j] + lq[3][j];
    float c = (float)max(s1 - s0, 1);
    float m = sm / c;
    float var = sq / c - m * m;
    mean[g * 64 + j] = m;
    rstd[g * 64 + j] = rsqrtf(var + 1e-5f);
  }
}

// ---------- per-layer: norm + relu + residual ----------
__global__ void k_fin(const float* __restrict__ h2, const int* __restrict__ batch,
                      const float* __restrict__ mean, const float* __restrict__ rstd,
                      const float* __restrict__ nw_, const float* __restrict__ nb_,
                      float* __restrict__ h) {
  int total = N_ * 64;
  for (int i = blockIdx.x * blockDim.x + threadIdx.x; i < total; i += gridDim.x * blockDim.x) {
    int n = i >> 6, j = i & 63;
    int g = batch[n];
    float val = nw_[j] * (h2[i] - mean[g * 64 + j]) * rstd[g * 64 + j] + nb_[j];
    h[i] = fmaxf(val, 0.f) + h[i];
  }
}

// ---------- launch ----------
extern "C" void kernel_launch(void* const* d_in, const int* in_sizes, int n_in,
                              void* d_out, int out_size, void* d_ws, size_t ws_size,
                              hipStream_t stream) {
  const float* x     = (const float*)d_in[0];
  const int*   eidx  = (const int*)d_in[1];
  const float* eattr = (const float*)d_in[2];
  const int*   batch = (const int*)d_in[3];
  const float* encW  = (const float*)d_in[4];
  const float* encB  = (const float*)d_in[5];
  const float* nodeW = (const float*)d_in[6];
  const float* nodeB = (const float*)d_in[7];
  const float* edgeW = (const float*)d_in[8];
  const float* edgeB = (const float*)d_in[9];
  const float* m1W   = (const float*)d_in[10];
  const float* m1B   = (const float*)d_in[11];
  const float* m2W   = (const float*)d_in[12];
  const float* m2B   = (const float*)d_in[13];
  const float* nw    = (const float*)d_in[14];
  const float* nb    = (const float*)d_in[15];

  float* h  = (float*)d_out;
  float* ws = (float*)d_ws;
  float* h2   = ws;                       // N*64
  float* ah   = h2 + N_ * 64;             // N*64
  float* aea  = ah + N_ * 64;             // N*16
  float* mean = aea + N_ * 16;            // G*64
  float* rstd = mean + GG * 64;           // G*64
  float* cst  = rstd + GG * 64;           // 3*CSTRIDE
  int* rowptr = (int*)(cst + 3 * CSTRIDE);   // N+1
  int* cntP   = rowptr + (N_ + 1);           // N
  int* bsum   = cntP + N_;                   // 128
  int* gstart = bsum + 128;                  // G+1
  int* adjS   = gstart + (GG + 1);           // E (src ids in CSR order)
  int* adjE   = adjS + E_;                   // E (edge ids in CSR order)

  const int* srcI = eidx;
  const int* dstI = eidx + E_;

  // boundaries + CSR build (once per call)
  k_gstart<<<512, 256, 0, stream>>>(batch, gstart);
  hipMemsetAsync(cntP, 0, (size_t)N_ * 4, stream);
  k_deg<<<1024, 256, 0, stream>>>(dstI, cntP);
  k_scan1<<<NB_SCAN, SCAN_B, 0, stream>>>(cntP, rowptr, bsum);
  k_scan2<<<1, SCAN_B, 0, stream>>>(bsum);
  k_scan3<<<NB_SCAN, SCAN_B, 0, stream>>>(rowptr, bsum);
  hipMemsetAsync(cntP, 0, (size_t)N_ * 4, stream);
  k_fill<<<1024, 256, 0, stream>>>(dstI, srcI, rowptr, cntP, adjS, adjE);
  k_aeag<<<1024, 256, 0, stream>>>(rowptr, adjE, eattr, aea);

  k_setup<<<3, 256, 0, stream>>>(nodeW, nodeB, edgeW, edgeB, m1W, m1B, cst);
  k_enc<<<1024, 256, 0, stream>>>(x, encW, encB, h);

  for (int l = 0; l < 3; ++l) {
    k_gather<<<2048, 256, 0, stream>>>(h, rowptr, adjS, ah);
    k_node<<<1024, 256, 0, stream>>>(h, ah, aea, rowptr, cst + l * CSTRIDE,
                                     m2W + l * 4096, m2B + l * 64, h2);
    k_gstats<<<GG, 256, 0, stream>>>(h2, gstart, mean, rstd);
    k_fin<<<2048, 256, 0, stream>>>(h2, batch, mean, rstd,
                                    nw + l * 64, nb + l * 64, h);
  }
}

// Round 8
// 754.914 us; speedup vs baseline: 6.4746x; 1.2767x over previous
//
#include <hip/hip_runtime.h>
#include <hip/hip_bf16.h>

#define N_   100000
#define E_   1200000
#define GG   1000
#define CSTRIDE 9344   // A(4096) + B(4096) + C(1024) + c0(64) + d0(64)
#define SCAN_B 1024
#define NB_SCAN ((N_ + SCAN_B - 1) / SCAN_B)   // 98
#define NTILE (N_ / 16)                        // 6250
#define WPK   14336                            // packed bf16 weights per layer

typedef short bf16x8 __attribute__((ext_vector_type(8)));
typedef float f32x4 __attribute__((ext_vector_type(4)));

__device__ __forceinline__ unsigned short bfrn(float x) {
  unsigned u = __float_as_uint(x);
  u += 0x7fffu + ((u >> 16) & 1u);
  return (unsigned short)(u >> 16);
}
__device__ __forceinline__ float blo(unsigned u) { return __uint_as_float(u << 16); }
__device__ __forceinline__ float bhi(unsigned u) { return __uint_as_float(u & 0xffff0000u); }

// ---------- graph boundaries from sorted batch ----------
__global__ void k_gstart(const int* __restrict__ batch, int* __restrict__ gstart) {
  for (int i = blockIdx.x * blockDim.x + threadIdx.x; i < N_; i += gridDim.x * blockDim.x) {
    int b = batch[i];
    if (i == 0) { for (int g = 0; g <= b; ++g) gstart[g] = 0; }
    else { int bp = batch[i - 1]; for (int g = bp + 1; g <= b; ++g) gstart[g] = i; }
    if (i == N_ - 1) { for (int g = b + 1; g <= GG; ++g) gstart[g] = N_; }
  }
}

// ---------- CSR build ----------
__global__ void k_deg(const int* __restrict__ dst, int* __restrict__ cnt) {
  for (int e = blockIdx.x * blockDim.x + threadIdx.x; e < E_; e += gridDim.x * blockDim.x)
    atomicAdd(&cnt[dst[e]], 1);
}

__global__ void k_scan1(const int* __restrict__ cnt, int* __restrict__ rowptr,
                        int* __restrict__ bsum) {
  __shared__ int s[SCAN_B];
  int t = threadIdx.x, i = blockIdx.x * SCAN_B + t;
  int v = (i < N_) ? cnt[i] : 0;
  s[t] = v;
  __syncthreads();
  for (int off = 1; off < SCAN_B; off <<= 1) {
    int x = (t >= off) ? s[t - off] : 0;
    __syncthreads();
    s[t] += x;
    __syncthreads();
  }
  if (i < N_) rowptr[i] = s[t] - v;
  if (t == SCAN_B - 1) bsum[blockIdx.x] = s[t];
}

__global__ void k_scan2(int* __restrict__ bsum) {
  __shared__ int s[SCAN_B];
  int t = threadIdx.x;
  int v = (t < NB_SCAN) ? bsum[t] : 0;
  s[t] = v;
  __syncthreads();
  for (int off = 1; off < SCAN_B; off <<= 1) {
    int x = (t >= off) ? s[t - off] : 0;
    __syncthreads();
    s[t] += x;
    __syncthreads();
  }
  if (t < NB_SCAN) bsum[t] = s[t] - v;
}

__global__ void k_scan3(int* __restrict__ rowptr, const int* __restrict__ bsum) {
  int t = threadIdx.x, i = blockIdx.x * SCAN_B + t;
  if (i < N_) rowptr[i] += bsum[blockIdx.x];
  if (i == 0) rowptr[N_] = E_;
}

__global__ void k_fill(const int* __restrict__ dst, const int* __restrict__ srcI,
                       const int* __restrict__ rowptr, int* __restrict__ pos,
                       int* __restrict__ adjS, int* __restrict__ adjE) {
  for (int e = blockIdx.x * blockDim.x + threadIdx.x; e < E_; e += gridDim.x * blockDim.x) {
    int d = dst[e];
    int slot = atomicAdd(&pos[d], 1);
    int p = rowptr[d] + slot;
    adjS[p] = srcI[e];
    adjE[p] = e;
  }
}

__global__ void k_degf(const int* __restrict__ rowptr, float* __restrict__ degf) {
  for (int n = blockIdx.x * blockDim.x + threadIdx.x; n < N_; n += gridDim.x * blockDim.x)
    degf[n] = (float)(rowptr[n + 1] - rowptr[n]);
}

// ---------- aea16[d][k] = bf16( sum of edge_attr over incoming edges ) ----------
__global__ void k_aeag(const int* __restrict__ rowptr, const int* __restrict__ adjE,
                       const float* __restrict__ ea, unsigned short* __restrict__ aea16) {
  int lane = threadIdx.x & 63, w = threadIdx.x >> 6;
  int q = lane >> 4, j = lane & 15;
  int gw = blockIdx.x * 4 + w, nwv = gridDim.x * 4;
  for (int n = gw; n < N_; n += nwv) {
    int rp = rowptr[n], rp1 = rowptr[n + 1];
    float acc = 0.f;
    for (int idx = rp + q; idx < rp1; idx += 4) {
      int e = adjE[idx];
      acc += ea[e * 16 + j];
    }
    acc += __shfl_xor(acc, 16);
    acc += __shfl_xor(acc, 32);
    if (q == 0) aea16[n * 16 + j] = bfrn(acc);
  }
}

// ---------- fold layer constants (fp32) ----------
__global__ void k_setup(const float* __restrict__ nodeW, const float* __restrict__ nodeB,
                        const float* __restrict__ edgeW, const float* __restrict__ edgeB,
                        const float* __restrict__ m1W, const float* __restrict__ m1B,
                        float* __restrict__ cst) {
  int l = blockIdx.x;
  __shared__ float sWn[4096], sWe[1024], sW1[8192];
  const float* Wn = nodeW + l * 4096;
  const float* We = edgeW + l * 1024;
  const float* W1 = m1W + l * 8192;
  for (int i = threadIdx.x; i < 4096; i += 256) sWn[i] = Wn[i];
  for (int i = threadIdx.x; i < 1024; i += 256) sWe[i] = We[i];
  for (int i = threadIdx.x; i < 8192; i += 256) sW1[i] = W1[i];
  __syncthreads();
  float* C = cst + l * CSTRIDE;
  int j = threadIdx.x & 63, q = threadIdx.x >> 6;
  for (int kk = 0; kk < 16; ++kk) {
    int k = q * 16 + kk;
    float a = 0.f, b = 0.f;
    for (int m = 0; m < 64; ++m) {
      float w = sWn[k * 64 + m];
      a += w * sW1[m * 64 + j];
      b += w * sW1[(64 + m) * 64 + j];
    }
    C[k * 64 + j] = a;
    C[4096 + k * 64 + j] = b;
  }
  if (q == 0) {
    for (int k = 0; k < 16; ++k) {
      float c = 0.f;
      for (int m = 0; m < 64; ++m) c += sWe[k * 64 + m] * sW1[(64 + m) * 64 + j];
      C[8192 + k * 64 + j] = c;
    }
  } else if (q == 1) {
    float c = 0.f;
    for (int m = 0; m < 64; ++m)
      c += (nodeB[l * 64 + m] + edgeB[l * 64 + m]) * sW1[(64 + m) * 64 + j];
    C[9216 + j] = c;
  } else if (q == 2) {
    float d = m1B[l * 64 + j];
    for (int m = 0; m < 64; ++m) d += nodeB[l * 64 + m] * sW1[m * 64 + j];
    C[9280 + j] = d;
  }
}

// ---------- pack folded weights into bf16 MFMA B-fragment layout ----------
// Layout per matrix: elem(ct,ks,lane,pos) = M[k][n], n=(lane&15)+16*ct,
// k=ks*32+(lane>>4)*8+pos. Offsets: A=0, B=4096, C=8192(2048, k>=16 zero), W2=10240.
__global__ void k_pack(const float* __restrict__ cst, const float* __restrict__ m2W,
                       unsigned short* __restrict__ wpk) {
  int l = blockIdx.x;
  const float* cl = cst + l * CSTRIDE;
  const float* w2 = m2W + l * 4096;
  for (int i = threadIdx.x; i < WPK; i += 256) {
    int mat, idx;
    if (i < 4096)       { mat = 0; idx = i; }
    else if (i < 8192)  { mat = 1; idx = i - 4096; }
    else if (i < 10240) { mat = 2; idx = i - 8192; }
    else                { mat = 3; idx = i - 10240; }
    int pos = idx & 7, lane = (idx >> 3) & 63;
    int n, k;
    if (mat == 2) {  // C: [4 ct][64 lane][8], single ks
      int ct = idx >> 9;
      n = (lane & 15) + 16 * ct;
      k = (lane >> 4) * 8 + pos;
    } else {
      int ks = (idx >> 9) & 1, ct = idx >> 10;
      n = (lane & 15) + 16 * ct;
      k = ks * 32 + (lane >> 4) * 8 + pos;
    }
    float v = 0.f;
    if (mat == 0) v = cl[k * 64 + n];
    else if (mat == 1) v = cl[4096 + k * 64 + n];
    else if (mat == 2) v = (k < 16) ? cl[8192 + k * 64 + n] : 0.f;
    else v = w2[k * 64 + n];
    wpk[l * WPK + i] = bfrn(v);
  }
}

// ---------- encoder (LDS broadcast, fp32) ----------
__global__ __launch_bounds__(256, 2) void k_enc(const float* __restrict__ x,
                                                const float* __restrict__ W,
                                                const float* __restrict__ b,
                                                float* __restrict__ out) {
  __shared__ float sW[4096];
  __shared__ float sb[64];
  __shared__ float xsh[4][64];
  for (int i = threadIdx.x; i < 4096; i += 256) sW[i] = W[i];
  if (threadIdx.x < 64) sb[threadIdx.x] = b[threadIdx.x];
  __syncthreads();
  int j = threadIdx.x & 63, w = threadIdx.x >> 6;
  int gw = blockIdx.x * 4 + w, nwv = gridDim.x * 4;
  for (int n = gw; n < N_; n += nwv) {
    xsh[w][j] = x[n * 64 + j];
    float acc = sb[j];
#pragma unroll
    for (int k = 0; k < 64; k += 4) {
      float4 xk = *(const float4*)&xsh[w][k];
      acc += xk.x * sW[(k + 0) * 64 + j];
      acc += xk.y * sW[(k + 1) * 64 + j];
      acc += xk.z * sW[(k + 2) * 64 + j];
      acc += xk.w * sW[(k + 3) * 64 + j];
    }
    out[n * 64 + j] = acc;
  }
}

// ---------- fp32 h -> bf16 mirror ----------
__global__ void k_cvt(const float* __restrict__ h, unsigned short* __restrict__ h16) {
  int total = N_ * 64;
  for (int i = blockIdx.x * blockDim.x + threadIdx.x; i < total; i += gridDim.x * blockDim.x)
    h16[i] = bfrn(h[i]);
}

// ---------- per-layer: pair-packed bf16 gather ----------
__global__ __launch_bounds__(256) void k_gather(const unsigned short* __restrict__ h16,
                                                const int* __restrict__ rowptr,
                                                const int* __restrict__ adjS,
                                                unsigned short* __restrict__ ah16) {
  int lane = threadIdx.x & 63;
  int a = lane & 31, q = lane >> 5;
  int gw = blockIdx.x * 4 + (threadIdx.x >> 6), nwv = gridDim.x * 4;
  for (int n = gw; n < N_; n += nwv) {
    int r0 = rowptr[n], r1 = rowptr[n + 1];
    float p0 = 0.f, p1 = 0.f, p2 = 0.f, p3 = 0.f;
    for (int base = r0; base < r1; base += 64) {
      int cnt = r1 - base;
      if (cnt > 64) cnt = 64;
      int idx = base + lane;
      int sv = (idx < r1) ? adjS[idx] : 0;
      int t = 0;
      for (; t + 3 < cnt; t += 4) {
        int s0 = __builtin_amdgcn_readlane(sv, t);
        int s1 = __builtin_amdgcn_readlane(sv, t + 1);
        int s2 = __builtin_amdgcn_readlane(sv, t + 2);
        int s3 = __builtin_amdgcn_readlane(sv, t + 3);
        int sA = q ? s1 : s0;
        int sB = q ? s3 : s2;
        unsigned u0 = *(const unsigned*)&h16[sA * 64 + a * 2];
        unsigned u1 = *(const unsigned*)&h16[sB * 64 + a * 2];
        p0 += blo(u0); p1 += bhi(u0);
        p2 += blo(u1); p3 += bhi(u1);
      }
      for (; t + 1 < cnt; t += 2) {
        int s0 = __builtin_amdgcn_readlane(sv, t);
        int s1 = __builtin_amdgcn_readlane(sv, t + 1);
        int sA = q ? s1 : s0;
        unsigned u0 = *(const unsigned*)&h16[sA * 64 + a * 2];
        p0 += blo(u0); p1 += bhi(u0);
      }
      if (t < cnt && q == 0) {
        int s0 = __builtin_amdgcn_readlane(sv, t);
        unsigned u0 = *(const unsigned*)&h16[s0 * 64 + a * 2];
        p0 += blo(u0); p1 += bhi(u0);
      }
    }
    float acc0 = p0 + p2, acc1 = p1 + p3;
    acc0 += __shfl_xor(acc0, 32);
    acc1 += __shfl_xor(acc1, 32);
    if (lane < 32) {
      unsigned u = (unsigned)bfrn(acc0) | ((unsigned)bfrn(acc1) << 16);
      *(unsigned*)&ah16[n * 64 + a * 2] = u;
    }
  }
}

// ---------- per-layer: MFMA node MLP ----------
// Wave handles 16 nodes. A-frags direct from global bf16; weights in LDS (frag layout);
// t transposed through XOR-swizzled per-wave LDS tile.
__global__ __launch_bounds__(256) void k_node(const unsigned short* __restrict__ h16,
                                              const unsigned short* __restrict__ ah16,
                                              const unsigned short* __restrict__ aea16,
                                              const float* __restrict__ degf,
                                              const unsigned short* __restrict__ wpk,
                                              const float* __restrict__ cstf,
                                              const float* __restrict__ b2,
                                              float* __restrict__ h2) {
  __shared__ unsigned short wlds[WPK];
  __shared__ float sc0[64], sd0[64], sb2[64];
  __shared__ unsigned short tbuf[4][2048];   // per-wave [16 rows][64 cols] bf16, XOR-swizzled
  for (int i = threadIdx.x; i < WPK; i += 256) wlds[i] = wpk[i];
  if (threadIdx.x < 64) {
    sc0[threadIdx.x] = cstf[9216 + threadIdx.x];
    sd0[threadIdx.x] = cstf[9280 + threadIdx.x];
    sb2[threadIdx.x] = b2[threadIdx.x];
  }
  __syncthreads();
  int lane = threadIdx.x & 63, w = threadIdx.x >> 6;
  int r16 = lane & 15, kc = lane >> 4;
  for (int t = blockIdx.x * 4 + w; t < NTILE; t += gridDim.x * 4) {
    int n0 = t * 16;
    // acc init: d0[c] + deg[row]*c0[c]
    float4 dg = *(const float4*)&degf[n0 + kc * 4];
    f32x4 acc[4];
#pragma unroll
    for (int ct = 0; ct < 4; ++ct) {
      float d0v = sd0[r16 + 16 * ct], c0v = sc0[r16 + 16 * ct];
      acc[ct][0] = d0v + dg.x * c0v;
      acc[ct][1] = d0v + dg.y * c0v;
      acc[ct][2] = d0v + dg.z * c0v;
      acc[ct][3] = d0v + dg.w * c0v;
    }
    // GEMM1: x @ A
#pragma unroll
    for (int ks = 0; ks < 2; ++ks) {
      bf16x8 ax = *(const bf16x8*)&h16[(n0 + r16) * 64 + ks * 32 + kc * 8];
#pragma unroll
      for (int ct = 0; ct < 4; ++ct)
        acc[ct] = __builtin_amdgcn_mfma_f32_16x16x32_bf16(
            ax, *(const bf16x8*)&wlds[(ct * 2 + ks) * 512 + lane * 8], acc[ct], 0, 0, 0);
    }
    // + ah @ B
#pragma unroll
    for (int ks = 0; ks < 2; ++ks) {
      bf16x8 ay = *(const bf16x8*)&ah16[(n0 + r16) * 64 + ks * 32 + kc * 8];
#pragma unroll
      for (int ct = 0; ct < 4; ++ct)
        acc[ct] = __builtin_amdgcn_mfma_f32_16x16x32_bf16(
            ay, *(const bf16x8*)&wlds[4096 + (ct * 2 + ks) * 512 + lane * 8], acc[ct], 0, 0, 0);
    }
    // + aea @ C (K=16 zero-padded to 32)
    {
      bf16x8 ae = {};
      if (kc < 2) ae = *(const bf16x8*)&aea16[(n0 + r16) * 16 + kc * 8];
#pragma unroll
      for (int ct = 0; ct < 4; ++ct)
        acc[ct] = __builtin_amdgcn_mfma_f32_16x16x32_bf16(
            ae, *(const bf16x8*)&wlds[8192 + ct * 512 + lane * 8], acc[ct], 0, 0, 0);
    }
    // relu -> t (bf16) into swizzled LDS tile (C-layout write)
#pragma unroll
    for (int ct = 0; ct < 4; ++ct) {
#pragma unroll
      for (int r = 0; r < 4; ++r) {
        int rr = kc * 4 + r, cc = r16 + 16 * ct;
        int byte = (rr * 128 + cc * 2) ^ ((rr & 7) << 4);
        tbuf[w][byte >> 1] = bfrn(fmaxf(acc[ct][r], 0.f));
      }
    }
    // GEMM2: t @ W2  (A-layout read from swizzled tile)
    f32x4 o[4];
#pragma unroll
    for (int ct = 0; ct < 4; ++ct) {
      float b2v = sb2[r16 + 16 * ct];
      o[ct][0] = b2v; o[ct][1] = b2v; o[ct][2] = b2v; o[ct][3] = b2v;
    }
#pragma unroll
    for (int ks = 0; ks < 2; ++ks) {
      int byte = (r16 * 128 + (ks * 32 + kc * 8) * 2) ^ ((r16 & 7) << 4);
      bf16x8 at = *(const bf16x8*)&tbuf[w][byte >> 1];
#pragma unroll
      for (int ct = 0; ct < 4; ++ct)
        o[ct] = __builtin_amdgcn_mfma_f32_16x16x32_bf16(
            at, *(const bf16x8*)&wlds[10240 + (ct * 2 + ks) * 512 + lane * 8], o[ct], 0, 0, 0);
    }
    // store h2 (C-layout: col=r16+16ct, row=kc*4+r)
#pragma unroll
    for (int ct = 0; ct < 4; ++ct) {
#pragma unroll
      for (int r = 0; r < 4; ++r)
        h2[(n0 + kc * 4 + r) * 64 + r16 + 16 * ct] = o[ct][r];
    }
  }
}

// ---------- per-layer: per-graph stats ----------
__global__ void k_gstats(const float* __restrict__ h2, const int* __restrict__ gstart,
                         float* __restrict__ mean, float* __restrict__ rstd) {
  int g = blockIdx.x;
  int s0 = gstart[g], s1 = gstart[g + 1];
  int j = threadIdx.x & 63, w = threadIdx.x >> 6;
  float sm = 0.f, sq = 0.f;
  for (int r = s0 + w; r < s1; r += 4) {
    float v = h2[r * 64 + j];
    sm += v;
    sq += v * v;
  }
  __shared__ float ls[4][64], lq[4][64];
  ls[w][j] = sm;
  lq[w][j] = sq;
  __syncthreads();
  if (w == 0) {
    sm = ls[0][j] + ls[1][j] + ls[2][j] + ls[3][j];
    sq = lq[0][j] + lq[1][j] + lq[2][j] + lq[3][j];
    float c = (float)max(s1 - s0, 1);
    float m = sm / c;
    float var = sq / c - m * m;
    mean[g * 64 + j] = m;
    rstd[g * 64 + j] = rsqrtf(var + 1e-5f);
  }
}

// ---------- per-layer: norm + relu + residual (writes h fp32 + h16 mirror) ----------
__global__ void k_fin(const float* __restrict__ h2, const int* __restrict__ batch,
                      const float* __restrict__ mean, const float* __restrict__ rstd,
                      const float* __restrict__ nw_, const float* __restrict__ nb_,
                      float* __restrict__ h, unsigned short* __restrict__ h16) {
  int total = N_ * 64;
  for (int i = blockIdx.x * blockDim.x + threadIdx.x; i < total; i += gridDim.x * blockDim.x) {
    int n = i >> 6, j = i & 63;
    int g = batch[n];
    float val = nw_[j] * (h2[i] - mean[g * 64 + j]) * rstd[g * 64 + j] + nb_[j];
    float nh = fmaxf(val, 0.f) + h[i];
    h[i] = nh;
    h16[i] = bfrn(nh);
  }
}

// ---------- launch ----------
extern "C" void kernel_launch(void* const* d_in, const int* in_sizes, int n_in,
                              void* d_out, int out_size, void* d_ws, size_t ws_size,
                              hipStream_t stream) {
  const float* x     = (const float*)d_in[0];
  const int*   eidx  = (const int*)d_in[1];
  const float* eattr = (const float*)d_in[2];
  const int*   batch = (const int*)d_in[3];
  const float* encW  = (const float*)d_in[4];
  const float* encB  = (const float*)d_in[5];
  const float* nodeW = (const float*)d_in[6];
  const float* nodeB = (const float*)d_in[7];
  const float* edgeW = (const float*)d_in[8];
  const float* edgeB = (const float*)d_in[9];
  const float* m1W   = (const float*)d_in[10];
  const float* m1B   = (const float*)d_in[11];
  const float* m2W   = (const float*)d_in[12];
  const float* m2B   = (const float*)d_in[13];
  const float* nw    = (const float*)d_in[14];
  const float* nb    = (const float*)d_in[15];

  float* h  = (float*)d_out;
  float* ws = (float*)d_ws;
  float* h2   = ws;                          // N*64 f32
  float* mean = h2 + N_ * 64;                // G*64
  float* rstd = mean + GG * 64;              // G*64
  float* cst  = rstd + GG * 64;              // 3*CSTRIDE f32
  float* degf = cst + 3 * CSTRIDE;           // N f32
  int* rowptr = (int*)(degf + N_);           // N+1
  int* cntP   = rowptr + (N_ + 1);           // N
  int* bsum   = cntP + N_;                   // 128
  int* gstart = bsum + 128;                  // G+1
  int* adjS   = gstart + (GG + 1);           // E
  unsigned short* h16   = (unsigned short*)(adjS + E_);  // N*64 bf16
  unsigned short* ah16  = h16 + N_ * 64;                 // N*64 bf16
  unsigned short* aea16 = ah16 + N_ * 64;                // N*16 bf16
  unsigned short* wpk   = aea16 + N_ * 16;               // 3*WPK bf16
  int* adjE = (int*)h2;   // alias: adjE only needed before first h2 write

  const int* srcI = eidx;
  const int* dstI = eidx + E_;

  // CSR + boundaries (once per call)
  k_gstart<<<512, 256, 0, stream>>>(batch, gstart);
  hipMemsetAsync(cntP, 0, (size_t)N_ * 4, stream);
  k_deg<<<1024, 256, 0, stream>>>(dstI, cntP);
  k_scan1<<<NB_SCAN, SCAN_B, 0, stream>>>(cntP, rowptr, bsum);
  k_scan2<<<1, SCAN_B, 0, stream>>>(bsum);
  k_scan3<<<NB_SCAN, SCAN_B, 0, stream>>>(rowptr, bsum);
  hipMemsetAsync(cntP, 0, (size_t)N_ * 4, stream);
  k_fill<<<1024, 256, 0, stream>>>(dstI, srcI, rowptr, cntP, adjS, adjE);
  k_aeag<<<1024, 256, 0, stream>>>(rowptr, adjE, eattr, aea16);
  k_degf<<<512, 256, 0, stream>>>(rowptr, degf);

  k_setup<<<3, 256, 0, stream>>>(nodeW, nodeB, edgeW, edgeB, m1W, m1B, cst);
  k_pack<<<3, 256, 0, stream>>>(cst, m2W, wpk);
  k_enc<<<1024, 256, 0, stream>>>(x, encW, encB, h);
  k_cvt<<<1024, 256, 0, stream>>>(h, h16);

  for (int l = 0; l < 3; ++l) {
    k_gather<<<2048, 256, 0, stream>>>(h16, rowptr, adjS, ah16);
    k_node<<<1024, 256, 0, stream>>>(h16, ah16, aea16, degf, wpk + l * WPK,
                                     cst + l * CSTRIDE, m2B + l * 64, h2);
    k_gstats<<<GG, 256, 0, stream>>>(h2, gstart, mean, rstd);
    k_fin<<<2048, 256, 0, stream>>>(h2, batch, mean, rstd,
                                    nw + l * 64, nb + l * 64, h, h16);
  }
}